// Round 5
// baseline (197.600 us; speedup 1.0000x reference)
//
#include <hip/hip_runtime.h>
#include <hip/hip_bf16.h>
#include <math.h>

#define KMIX 16
#define DIM  16
#define TPW  8          // 16-sample tiles per wave
#define TRI_IDX(i,j) (((i)*((i)+1))/2 + (j))

typedef _Float16 half8 __attribute__((ext_vector_type(8)));
typedef float    f32x4 __attribute__((ext_vector_type(4)));

// ---------------------------------------------------------------------------
// Fused kernel. R2/R3/R4 showed a separate 1-wave precompute dispatch costs
// ~38 us REGARDLESS of its body (three different implementations, same
// time) -> the dispatch/serialization is the cost, not the math. So every
// block redundantly precomputes the mixture constants (lane k<16 of wave 0,
// register-resident in-place Cholesky + triangular inverse, ~2k exec-masked
// instructions ~= 1-3 us aggregate across 1024 blocks), publishes to LDS,
// then all waves run the MFMA main loop. No workspace, one graph node.
// ---------------------------------------------------------------------------
__global__ __launch_bounds__(256) void gmm_fused(
    const float* __restrict__ samples,
    const float* __restrict__ Phi, const float* __restrict__ mu,
    const float* __restrict__ Sigma,
    float* __restrict__ out, int N, int ntiles)
{
    __shared__ float sLi[KMIX][DIM][DIM];   // L^{-1}, upper zero
    __shared__ float sNB[KMIX][DIM];        // -b = -L^{-1} mu
    __shared__ float sCk[KMIX];             // Phi / sqrt(2*pi*det)

    const int tid = threadIdx.x;

    // ---- Phase 1: per-block redundant precompute (lane k<16 of wave 0) ----
    if (tid < KMIX) {
        const int k = tid;
        float a[136], rd[DIM];

        #pragma unroll
        for (int i = 0; i < DIM; ++i)
            #pragma unroll
            for (int j = 0; j <= i; ++j)
                a[TRI_IDX(i, j)] = Sigma[k * 256 + i * 16 + j];

        // Left-looking Cholesky, in place, reciprocal diagonal kept.
        #pragma unroll
        for (int i = 0; i < DIM; ++i) {
            #pragma unroll
            for (int j = 0; j <= i; ++j) {
                float s = a[TRI_IDX(i, j)];
                #pragma unroll
                for (int m = 0; m < j; ++m)
                    s -= a[TRI_IDX(i, m)] * a[TRI_IDX(j, m)];
                if (j == i) {
                    const float d = __builtin_amdgcn_sqrtf(s);
                    a[TRI_IDX(i, i)] = d;
                    rd[i] = __builtin_amdgcn_rcpf(d);
                } else {
                    a[TRI_IDX(i, j)] = s * rd[j];
                }
            }
        }

        // In-place triangular inversion: a <- L^{-1}.
        // (c ascending, r ascending: (r,c) reads a[r][m] m in [c,r-1] — cols
        // > c untouched, m=c read-before-write — and a[m][c] already final.)
        #pragma unroll
        for (int c = 0; c < DIM; ++c) {
            a[TRI_IDX(c, c)] = rd[c];
            #pragma unroll
            for (int r = c + 1; r < DIM; ++r) {
                float s = 0.0f;
                #pragma unroll
                for (int m = c; m < r; ++m)
                    s += a[TRI_IDX(r, m)] * a[TRI_IDX(m, c)];
                a[TRI_IDX(r, c)] = -s * rd[r];
            }
        }

        float invd = 1.0f;
        #pragma unroll
        for (int i = 0; i < DIM; ++i) invd *= rd[i];
        sCk[k] = Phi[k] * 0.3989422804014327f * invd;

        float mv[DIM];
        #pragma unroll
        for (int j = 0; j < DIM; ++j) mv[j] = mu[k * DIM + j];
        #pragma unroll
        for (int r = 0; r < DIM; ++r) {
            float b = 0.0f;
            #pragma unroll
            for (int j = 0; j <= r; ++j) b += a[TRI_IDX(r, j)] * mv[j];
            sNB[k][r] = -b;
            #pragma unroll
            for (int j = 0; j < DIM; ++j)
                sLi[k][r][j] = (j <= r) ? a[TRI_IDX(r, j)] : 0.0f;
        }
    }
    __syncthreads();

    // ---- Phase 2: per-wave fragment pack + MFMA main loop ----
    const int lane = tid & 63;
    const int wave = blockIdx.x * 4 + (tid >> 6);
    const int n = lane & 15;          // sample column within tile
    const int quad = lane >> 4;
    const int m = n;                  // A-operand row for this lane

    // A fragments: verified 16x16x32 layout A[m=lane&15][k=quad*8+j],
    // W~ = [L^{-1} | -b | 0-pad].
    half8 afrag[KMIX];
    #pragma unroll
    for (int mix = 0; mix < KMIX; ++mix) {
        half8 h;
        #pragma unroll
        for (int j = 0; j < 8; ++j) {
            float v;
            if (quad == 0)      v = sLi[mix][m][j];
            else if (quad == 1) v = sLi[mix][m][8 + j];
            else if (quad == 2) v = (j == 0) ? sNB[mix][m] : 0.0f;
            else                v = 0.0f;
            h[j] = (_Float16)v;
        }
        afrag[mix] = h;
    }
    float ck[KMIX];
    #pragma unroll
    for (int mix = 0; mix < KMIX; ++mix) ck[mix] = sCk[mix];

    const f32x4 zero = {0.0f, 0.0f, 0.0f, 0.0f};

    for (int t = 0; t < TPW; ++t) {
        const int tile = wave * TPW + t;
        if (tile >= ntiles) break;
        const int s0 = tile * 16;

        // B frag: B[k=quad*8+j][n] = x~[sample n][k]; quad2 j=0 is the
        // augmented 1 that folds -b.
        half8 bfrag;
        #pragma unroll
        for (int j = 0; j < 8; ++j) bfrag[j] = (_Float16)0.0f;
        if (quad < 2) {
            int sidx = s0 + n; if (sidx >= N) sidx = N - 1;
            const float4* p = (const float4*)(samples + (size_t)sidx * DIM + quad * 8);
            const float4 u = p[0], v = p[1];
            bfrag[0] = (_Float16)u.x; bfrag[1] = (_Float16)u.y;
            bfrag[2] = (_Float16)u.z; bfrag[3] = (_Float16)u.w;
            bfrag[4] = (_Float16)v.x; bfrag[5] = (_Float16)v.y;
            bfrag[6] = (_Float16)v.z; bfrag[7] = (_Float16)v.w;
        } else if (quad == 2) {
            bfrag[0] = (_Float16)1.0f;
        }

        float sum = 0.0f;
        #pragma unroll
        for (int mix = 0; mix < KMIX; ++mix) {
            const f32x4 d = __builtin_amdgcn_mfma_f32_16x16x32_f16(
                afrag[mix], bfrag, zero, 0, 0, 0);
            float q = d[0] * d[0];
            q = fmaf(d[1], d[1], q);
            q = fmaf(d[2], d[2], q);
            q = fmaf(d[3], d[3], q);
            q += __shfl_xor(q, 16, 64);
            q += __shfl_xor(q, 32, 64);
            sum = fmaf(ck[mix], __expf(-0.5f * q), sum);
        }

        const int sidx = s0 + n;
        if (quad == 0 && sidx < N) out[sidx] = -__logf(sum);
    }
}

extern "C" void kernel_launch(void* const* d_in, const int* in_sizes, int n_in,
                              void* d_out, int out_size, void* d_ws, size_t ws_size,
                              hipStream_t stream)
{
    const float* samples = (const float*)d_in[0];
    const float* Phi     = (const float*)d_in[1];
    const float* mu      = (const float*)d_in[2];
    const float* Sigma   = (const float*)d_in[3];
    float* out = (float*)d_out;
    const int N = in_sizes[0] / DIM;

    const int ntiles = (N + 15) / 16;               // 32768
    const int waves  = (ntiles + TPW - 1) / TPW;    // 4096
    const int blocks = (waves + 3) / 4;             // 1024

    gmm_fused<<<blocks, 256, 0, stream>>>(samples, Phi, mu, Sigma, out, N, ntiles);
}

// Round 6
// 99.914 us; speedup vs baseline: 1.9777x; 1.9777x over previous
//
#include <hip/hip_runtime.h>
#include <hip/hip_bf16.h>
#include <math.h>

#define KMIX 16
#define DIM  16
#define TPW  8          // 16-sample tiles per wave in gmm_main

typedef _Float16 half8 __attribute__((ext_vector_type(8)));
typedef float    f32x4 __attribute__((ext_vector_type(4)));

// ---------------------------------------------------------------------------
// Precompute, cooperative: 4 blocks x 64 threads; each 16-lane group owns one
// mixture (k = blockIdx*4 + lane/16), lane r owns ROW r. R5 proved the
// per-lane a[136] Cholesky executes ~35 us (scratch-resident array on a
// 1-wave serial chain). Here every per-lane array is 16 floats with
// compile-time indices -> pure VGPR; cross-lane data moves via __shfl
// broadcasts (no LDS, no barriers, no scratch).
//   Cholesky (right-looking by column, rank-1 updates via shfl of the
//   freshly-scaled column) -> L row in l[]; then in-register triangular
//   inverse (row m of V broadcast as finalized) -> V = L^{-1} row in v[];
//   b = V mu; coeff = Phi * rsqrt(2pi)/prod(diag); pack A-fragments
//   straight from registers (output lanes {q*16+r} all source row r).
// ---------------------------------------------------------------------------
__global__ __launch_bounds__(64) void gmm_precompute(
    const float* __restrict__ Phi, const float* __restrict__ mu,
    const float* __restrict__ Sigma,
    _Float16* __restrict__ wsA, float* __restrict__ wsC)
{
    const int lane = threadIdx.x;
    const int r    = lane & 15;
    const int base = lane & 48;                 // 16-lane group base in wave
    const int k    = blockIdx.x * 4 + (lane >> 4);

    // Row r of Sigma_k.
    float l[DIM];
    {
        const float4* p = (const float4*)(Sigma + k * 256 + r * 16);
        const float4 a = p[0], b = p[1], c = p[2], d = p[3];
        l[0]=a.x;  l[1]=a.y;  l[2]=a.z;  l[3]=a.w;
        l[4]=b.x;  l[5]=b.y;  l[6]=b.z;  l[7]=b.w;
        l[8]=c.x;  l[9]=c.y;  l[10]=c.z; l[11]=c.w;
        l[12]=d.x; l[13]=d.y; l[14]=d.z; l[15]=d.w;
    }

    // Cholesky: after step j, l[j] on lanes r>=j is final L[r][j].
    float rd_own = 0.0f;                        // rcp(L[r][r]), set at step r
    #pragma unroll
    for (int j = 0; j < DIM; ++j) {
        const float dj  = __builtin_amdgcn_sqrtf(l[j]);   // meaningful on lane j
        const float rdj = __builtin_amdgcn_rcpf(dj);
        if (r == j) { l[j] = dj; rd_own = rdj; }
        const float rdb = __shfl(rdj, base + j, 64);
        if (r > j) l[j] *= rdb;                 // final L[r][j]
        #pragma unroll
        for (int c = j + 1; c < DIM; ++c) {
            const float Lcj = __shfl(l[j], base + c, 64);  // L[c][j]
            if (r >= c) l[c] = fmaf(-l[j], Lcj, l[c]);     // rank-1 update
        }
    }

    // Triangular inverse V = L^{-1}, lane r builds row r.
    // acc[c] accumulates sum_{m=c}^{r-1} L[r][m] * V[m][c].
    float v[DIM], acc[DIM];
    #pragma unroll
    for (int c = 0; c < DIM; ++c) { v[c] = 0.0f; acc[c] = 0.0f; }
    #pragma unroll
    for (int m = 0; m < DIM; ++m) {
        if (r == m) {                           // finalize row m
            #pragma unroll
            for (int c = 0; c < DIM; ++c)
                if (c < m) v[c] = -rd_own * acc[c];
            v[m] = rd_own;
        }
        #pragma unroll
        for (int c = 0; c <= m; ++c) {          // broadcast row m, accumulate
            const float Vmc = __shfl(v[c], base + m, 64);
            if (r > m) acc[c] = fmaf(l[m], Vmc, acc[c]);
        }
    }

    // coeff = Phi / (sqrt(2*pi) * prod diag L)  (prod rd across the group)
    float prod = rd_own;
    prod *= __shfl_xor(prod, 1, 64);
    prod *= __shfl_xor(prod, 2, 64);
    prod *= __shfl_xor(prod, 4, 64);
    prod *= __shfl_xor(prod, 8, 64);
    if (r == 0) wsC[k] = Phi[k] * 0.3989422804014327f * prod;

    // b_r = sum_c V[r][c] mu[c]   (v[c]=0 for c>r, so no predicate needed)
    float b = 0.0f;
    {
        const float4* pm = (const float4*)(mu + k * DIM);
        const float4 m0 = pm[0], m1 = pm[1], m2 = pm[2], m3 = pm[3];
        const float mv[DIM] = {m0.x,m0.y,m0.z,m0.w, m1.x,m1.y,m1.z,m1.w,
                               m2.x,m2.y,m2.z,m2.w, m3.x,m3.y,m3.z,m3.w};
        #pragma unroll
        for (int c = 0; c < DIM; ++c) b = fmaf(v[c], mv[c], b);
    }

    // Pack A-operand fragments (verified 16x16x32 A layout:
    // A[m=lane&15][k=quad*8+j], W~ = [L^{-1} | -b | 0]). Output lanes
    // {q*16 + r} all need row r -> this lane writes all four.
    half8 h0, h1, h2, h3;
    #pragma unroll
    for (int j = 0; j < 8; ++j) {
        h0[j] = (_Float16)v[j];
        h1[j] = (_Float16)v[8 + j];
        h2[j] = (_Float16)0.0f;
        h3[j] = (_Float16)0.0f;
    }
    h2[0] = (_Float16)(-b);
    half8* W = (half8*)wsA + k * 64;
    W[r]      = h0;
    W[16 + r] = h1;
    W[32 + r] = h2;
    W[48 + r] = h3;
}

// ---------------------------------------------------------------------------
// Main (unchanged, verified since R3): per wave, per 16-sample tile: build
// B frag = [x;1;0-pad], one MFMA per mixture, q = 4 square-FMAs +
// shfl_xor(16) + shfl_xor(32), sum_k c_k exp(-q/2).
// ---------------------------------------------------------------------------
__global__ __launch_bounds__(256) void gmm_main(
    const float* __restrict__ samples,
    const _Float16* __restrict__ wsA, const float* __restrict__ wsC,
    float* __restrict__ out, int N, int ntiles)
{
    const int lane = threadIdx.x & 63;
    const int wave = blockIdx.x * (blockDim.x >> 6) + (threadIdx.x >> 6);
    const int n = lane & 15;          // sample column within tile
    const int quad = lane >> 4;

    half8 afrag[KMIX];
    #pragma unroll
    for (int mix = 0; mix < KMIX; ++mix)
        afrag[mix] = ((const half8*)wsA)[mix * 64 + lane];
    float ck[KMIX];
    #pragma unroll
    for (int mix = 0; mix < KMIX; ++mix) ck[mix] = wsC[mix];

    const f32x4 zero = {0.0f, 0.0f, 0.0f, 0.0f};

    for (int t = 0; t < TPW; ++t) {
        const int tile = wave * TPW + t;
        if (tile >= ntiles) break;
        const int s0 = tile * 16;

        half8 bfrag;
        #pragma unroll
        for (int j = 0; j < 8; ++j) bfrag[j] = (_Float16)0.0f;
        if (quad < 2) {
            int sidx = s0 + n; if (sidx >= N) sidx = N - 1;
            const float4* p = (const float4*)(samples + (size_t)sidx * DIM + quad * 8);
            const float4 u = p[0], v = p[1];
            bfrag[0] = (_Float16)u.x; bfrag[1] = (_Float16)u.y;
            bfrag[2] = (_Float16)u.z; bfrag[3] = (_Float16)u.w;
            bfrag[4] = (_Float16)v.x; bfrag[5] = (_Float16)v.y;
            bfrag[6] = (_Float16)v.z; bfrag[7] = (_Float16)v.w;
        } else if (quad == 2) {
            bfrag[0] = (_Float16)1.0f;   // augmented k=16 -> folds -b
        }

        float sum = 0.0f;
        #pragma unroll
        for (int mix = 0; mix < KMIX; ++mix) {
            const f32x4 d = __builtin_amdgcn_mfma_f32_16x16x32_f16(
                afrag[mix], bfrag, zero, 0, 0, 0);
            float q = d[0] * d[0];
            q = fmaf(d[1], d[1], q);
            q = fmaf(d[2], d[2], q);
            q = fmaf(d[3], d[3], q);
            q += __shfl_xor(q, 16, 64);
            q += __shfl_xor(q, 32, 64);
            sum = fmaf(ck[mix], __expf(-0.5f * q), sum);
        }

        const int sidx = s0 + n;
        if (quad == 0 && sidx < N) out[sidx] = -__logf(sum);
    }
}

extern "C" void kernel_launch(void* const* d_in, const int* in_sizes, int n_in,
                              void* d_out, int out_size, void* d_ws, size_t ws_size,
                              hipStream_t stream)
{
    const float* samples = (const float*)d_in[0];
    const float* Phi     = (const float*)d_in[1];
    const float* mu      = (const float*)d_in[2];
    const float* Sigma   = (const float*)d_in[3];
    float* out = (float*)d_out;
    const int N = in_sizes[0] / DIM;

    _Float16* wsA = (_Float16*)d_ws;                       // 16*64*8 halves = 16 KB
    float* wsC = (float*)((char*)d_ws + KMIX * 64 * 8 * sizeof(_Float16));

    gmm_precompute<<<4, 64, 0, stream>>>(Phi, mu, Sigma, wsA, wsC);

    const int ntiles = (N + 15) / 16;
    const int waves  = (ntiles + TPW - 1) / TPW;
    const int blocks = (waves + 3) / 4;
    gmm_main<<<blocks, 256, 0, stream>>>(samples, wsA, wsC, out, N, ntiles);
}